// Round 4
// baseline (670.881 us; speedup 1.0000x reference)
//
#include <hip/hip_runtime.h>
#include <math.h>

// B=2, S=2048, H=1024, NH=16, HD=64
#define Ss  2048
#define Hh  1024

typedef unsigned short u16;
typedef __attribute__((ext_vector_type(8))) short short8;
typedef __attribute__((ext_vector_type(4))) float fx4;

__device__ __forceinline__ u16 f2bf(float f) {
  unsigned int u = __float_as_uint(f);
  u = (u + 0x7fffu + ((u >> 16) & 1u)) >> 16;
  return (u16)u;
}

__device__ __forceinline__ void gld_lds16(const u16* g, u16* l) {
  __builtin_amdgcn_global_load_lds(
      (const __attribute__((address_space(1))) unsigned int*)(const unsigned int*)g,
      (__attribute__((address_space(3))) unsigned int*)(unsigned int*)l, 16, 0, 0);
}

#define MFMA16(a,b,c) __builtin_amdgcn_mfma_f32_16x16x32_bf16((a),(b),(c),0,0,0)

// ---- fused prep: cast q/k/v (12288 blocks) + cast weights (4096 blocks) ----
__global__ __launch_bounds__(256) void prep(
    const float* __restrict__ q, const float* __restrict__ k,
    const float* __restrict__ v, const float* __restrict__ wq,
    const float* __restrict__ wk, const float* __restrict__ wv,
    const float* __restrict__ wo,
    u16* __restrict__ oq, u16* __restrict__ ok, u16* __restrict__ ov,
    u16* __restrict__ owq, u16* __restrict__ owk, u16* __restrict__ owv,
    u16* __restrict__ owo) {
  const int bid = blockIdx.x;
  const float* in; u16* out; int x;
  if (bid < 12288) {
    const int z = bid >> 12; x = bid & 4095;
    in = z == 0 ? q : (z == 1 ? k : v);
    out = z == 0 ? oq : (z == 1 ? ok : ov);
  } else {
    const int t = bid - 12288, z = t >> 10; x = t & 1023;
    in = z == 0 ? wq : (z == 1 ? wk : (z == 2 ? wv : wo));
    out = z == 0 ? owq : (z == 1 ? owk : (z == 2 ? owv : owo));
  }
  const int i = (x * 256 + threadIdx.x) * 4;
  const float4 vv = *(const float4*)(in + i);
  ushort4 r; r.x = f2bf(vv.x); r.y = f2bf(vv.y); r.z = f2bf(vv.z); r.w = f2bf(vv.w);
  *(ushort4*)(out + i) = r;
}

// ---- GEMM: C[M,N] = A[M,K]@W[N,K]^T + bias, K=N=1024, 128x128 tile --------
template <int MODE>
__device__ __forceinline__ void gemm_core(const u16* __restrict__ A,
    const u16* __restrict__ W, const float* __restrict__ bias,
    void* __restrict__ out, float scale) {
  __shared__ __align__(16) u16 As[2][4096];
  __shared__ __align__(16) u16 Bs[2][4096];
  const int tid = threadIdx.x;
  const int w = tid >> 6, lane = tid & 63, ln = lane & 15, quad = lane >> 4;
  const int i0 = blockIdx.y * 128, j0 = blockIdx.x * 128;
  const int wr = (w & 1) * 64, wc = (w >> 1) * 64;
  fx4 acc[4][4] = {};
  const int L0 = w * 64 + lane, L1 = L0 + 256;
  const u16* sa0 = A + (size_t)(i0 + (L0 & 127)) * 1024 + (L0 >> 7) * 8;
  const u16* sa1 = A + (size_t)(i0 + (L1 & 127)) * 1024 + (L1 >> 7) * 8;
  const u16* sb0 = W + (size_t)(j0 + (L0 & 127)) * 1024 + (L0 >> 7) * 8;
  const u16* sb1 = W + (size_t)(j0 + (L1 & 127)) * 1024 + (L1 >> 7) * 8;
  const int d0 = (w * 64) * 8, d1 = (256 + w * 64) * 8;

  // prologue: stage k-tile 0 into buffer 0
  gld_lds16(sa0, &As[0][d0]); gld_lds16(sa1, &As[0][d1]);
  gld_lds16(sb0, &Bs[0][d0]); gld_lds16(sb1, &Bs[0][d1]);
  __syncthreads();

  for (int k0 = 0; k0 < 1024; k0 += 32) {
    const int cur = (k0 >> 5) & 1;
    if (k0 + 32 < 1024) {
      const int nb = cur ^ 1;
      gld_lds16(sa0 + k0 + 32, &As[nb][d0]); gld_lds16(sa1 + k0 + 32, &As[nb][d1]);
      gld_lds16(sb0 + k0 + 32, &Bs[nb][d0]); gld_lds16(sb1 + k0 + 32, &Bs[nb][d1]);
    }
    short8 a[4], b[4];
#pragma unroll
    for (int t = 0; t < 4; ++t) {
      a[t] = *(const short8*)&As[cur][(quad * 128 + wr + t * 16 + ln) * 8];
      b[t] = *(const short8*)&Bs[cur][(quad * 128 + wc + t * 16 + ln) * 8];
    }
#pragma unroll
    for (int mt = 0; mt < 4; ++mt)
#pragma unroll
      for (int nt = 0; nt < 4; ++nt)
        acc[mt][nt] = MFMA16(a[mt], b[nt], acc[mt][nt]);
    __syncthreads();  // drains staging of next tile; protects buffer reuse
  }
#pragma unroll
  for (int nt = 0; nt < 4; ++nt) {
    const int col = j0 + wc + nt * 16 + ln;
    const float bv = bias[col];
#pragma unroll
    for (int mt = 0; mt < 4; ++mt)
#pragma unroll
      for (int r = 0; r < 4; ++r) {
        const int row = i0 + wr + mt * 16 + quad * 4 + r;
        const float val = (acc[mt][nt][r] + bv) * scale;
        if (MODE == 1) {
          const int bb = row >> 11, s = row & 2047, h = col >> 6, d = col & 63;
          ((u16*)out)[((size_t)(bb * 16 + h) * 2048 + s) * 64 + d] = f2bf(val);
        } else {
          ((float*)out)[(size_t)row * 1024 + col] = val;
        }
      }
  }
}

__global__ __launch_bounds__(256) void gemm_qkv(
    const u16* xq, const u16* xk, const u16* xv,
    const u16* wq, const u16* wk, const u16* wv,
    const float* bq, const float* bk, const float* bv,
    u16* q, u16* k, u16* v) {
  const int z = blockIdx.z;
  const u16* A = z == 0 ? xq : (z == 1 ? xk : xv);
  const u16* W = z == 0 ? wq : (z == 1 ? wk : wv);
  const float* bb = z == 0 ? bq : (z == 1 ? bk : bv);
  u16* o = z == 0 ? q : (z == 1 ? k : v);
  const float sc = z == 0 ? 0.125f : 1.0f;
  gemm_core<1>(A, W, bb, o, sc);
}

__global__ __launch_bounds__(256) void gemm_o(const u16* ctx, const u16* wo,
                                              const float* ob, float* out) {
  gemm_core<0>(ctx, wo, ob, out, 1.0f);
}

// ---- V transpose: (bh,S,HD) -> (bh,HD,S), bf16 -----------------------------
__global__ __launch_bounds__(256) void transpose_v(const u16* __restrict__ v,
                                                   u16* __restrict__ vt) {
  __shared__ u16 T[64][72];
  const int tid = threadIdx.x;
  const int bh = blockIdx.y, s0 = blockIdx.x * 64;
#pragma unroll
  for (int i = 0; i < 2; ++i) {
    const int L = i * 256 + tid, key = L >> 3, dc = L & 7;
    const uint4 val = *(const uint4*)&v[((size_t)bh * 2048 + s0 + key) * 64 + dc * 8];
    *(uint4*)&T[key][dc * 8] = val;
  }
  __syncthreads();
#pragma unroll
  for (int i = 0; i < 2; ++i) {
    const int L = i * 256 + tid, d = L >> 3, kc = L & 7;
    u16 tmp[8];
#pragma unroll
    for (int j = 0; j < 8; ++j) tmp[j] = T[kc * 8 + j][d];
    *(uint4*)&vt[((size_t)bh * 64 + d) * 2048 + s0 + kc * 8] = *(const uint4*)tmp;
  }
}

// ---- flash attention: 64 q-rows/block (16/wave), 64-key tiles --------------
// K fragments read from global into REGISTERS, software-pipelined one tile
// ahead (issued right after the QK MFMAs that kill the old values -> full
// softmax+PV+barrier of latency cover). V stays LDS double-buffered.
__global__ __launch_bounds__(256, 4) void attn(const u16* __restrict__ Qb,
    const u16* __restrict__ Kb, const u16* __restrict__ VT,
    const float* __restrict__ bias, const int* __restrict__ kpm,
    u16* __restrict__ ctx) {
  __shared__ __align__(16) u16 Vs[2][4096];  // [kc0..7][d0..63]*8
  __shared__ __align__(16) u16 Ps[4096];     // [kc0..7][q0..63]*8 (wave-private rows)
  const int tid = threadIdx.x;
  const int w = tid >> 6, lane = tid & 63, ln = lane & 15, quad = lane >> 4;
  const int q0 = blockIdx.x * 64;
  const int hb = blockIdx.y, h = hb >> 1, b = hb & 1, bh = b * 16 + h;
  const int wr = w * 16;            // wave's 16 q-rows within tile

  short8 qf[2];                      // B-frag: col = q = wr+ln, c = ks*32+quad*8
#pragma unroll
  for (int ks = 0; ks < 2; ++ks)
    qf[ks] = *(const short8*)&Qb[((size_t)bh * 2048 + q0 + wr + ln) * 64 +
                                 ks * 32 + quad * 8];
  float mi = -3.0e38f, li = 0.f;     // per-lane: q = q0+wr+ln
  fx4 O[4] = {};                     // O[nt][r]: q = quad*4+r, d = nt*16+ln

  const int L0 = w * 64 + lane, L1 = L0 + 256;
  const u16* sv0 = VT + ((size_t)bh * 64 + (L0 & 63)) * 2048 + (L0 >> 6) * 8;
  const u16* sv1 = VT + ((size_t)bh * 64 + (L1 & 63)) * 2048 + (L1 >> 6) * 8;
  const int d0 = (w * 64) * 8, d1 = (256 + w * 64) * 8;

  // per-lane K fragment base: key = kt + nt*16 + ln, d = ks*32 + quad*8 (+0..7)
  const u16* kb_l = Kb + ((size_t)bh * 2048 + ln) * 64 + quad * 8;
  // per-lane bias base: row q = q0+wr+ln, cols kt + nt*16 + quad*4 (+0..3)
  const float* bp = bias + (size_t)h * Ss * Ss + (size_t)(q0 + wr + ln) * Ss + quad * 4;
  const int* mp = kpm + b * Ss + quad * 4;

  // prologue: stage V tile 0; K fragments for tile 0; bias+mask for tile 0
  gld_lds16(sv0, &Vs[0][d0]); gld_lds16(sv1, &Vs[0][d1]);
  short8 kf[2][4];
#pragma unroll
  for (int ks = 0; ks < 2; ++ks)
#pragma unroll
    for (int nt = 0; nt < 4; ++nt)
      kf[ks][nt] = *(const short8*)(kb_l + nt * 1024 + ks * 32);
  fx4 bm[4];
#pragma unroll
  for (int nt = 0; nt < 4; ++nt) {
    const float4 bv = *(const float4*)(bp + nt * 16);
    const int4 mv = *(const int4*)(mp + nt * 16);
    bm[nt][0] = bv.x + (mv.x ? -1.0e30f : 0.0f);
    bm[nt][1] = bv.y + (mv.y ? -1.0e30f : 0.0f);
    bm[nt][2] = bv.z + (mv.z ? -1.0e30f : 0.0f);
    bm[nt][3] = bv.w + (mv.w ? -1.0e30f : 0.0f);
  }
  __syncthreads();

  for (int kt = 0; kt < Ss; kt += 64) {
    const int cur = (kt >> 6) & 1;
    if (kt + 64 < Ss) {
      const int nb = cur ^ 1;
      gld_lds16(sv0 + kt + 64, &Vs[nb][d0]);
      gld_lds16(sv1 + kt + 64, &Vs[nb][d1]);
    }
    const int kn = (kt + 64 < Ss) ? kt + 64 : kt;
    fx4 bmn[4];
#pragma unroll
    for (int nt = 0; nt < 4; ++nt) {
      const float4 bv = *(const float4*)(bp + kn + nt * 16);
      const int4 mv = *(const int4*)(mp + kn + nt * 16);
      bmn[nt][0] = bv.x + (mv.x ? -1.0e30f : 0.0f);
      bmn[nt][1] = bv.y + (mv.y ? -1.0e30f : 0.0f);
      bmn[nt][2] = bv.z + (mv.z ? -1.0e30f : 0.0f);
      bmn[nt][3] = bv.w + (mv.w ? -1.0e30f : 0.0f);
    }

    // S'[k][q] = K*Q with the kf prefetched LAST iteration:
    // lane holds k = kt + nt*16 + quad*4 + r, q = q0+wr+ln
    fx4 S[4] = {};
#pragma unroll
    for (int ks = 0; ks < 2; ++ks)
#pragma unroll
      for (int nt = 0; nt < 4; ++nt)
        S[nt] = MFMA16(kf[ks][nt], qf[ks], S[nt]);

    // prefetch NEXT tile's K fragments (old kf dead after the MFMAs above;
    // WAR dependence keeps these from hoisting; softmax+PV covers latency)
    {
      const u16* kp8 = kb_l + (size_t)kn * 64;
#pragma unroll
      for (int ks = 0; ks < 2; ++ks)
#pragma unroll
        for (int nt = 0; nt < 4; ++nt)
          kf[ks][nt] = *(const short8*)(kp8 + nt * 1024 + ks * 32);
    }

    // lane-local softmax over the lane's 16 scores
    float pmax = -3.0e38f;
#pragma unroll
    for (int nt = 0; nt < 4; ++nt)
#pragma unroll
      for (int r = 0; r < 4; ++r) {
        S[nt][r] += bm[nt][r];
        pmax = fmaxf(pmax, S[nt][r]);
      }
    pmax = fmaxf(pmax, __shfl_xor(pmax, 16));
    pmax = fmaxf(pmax, __shfl_xor(pmax, 32));

    // defer-max: only rescale when the running max grew by > 8
    if (!__all(pmax <= mi + 8.0f)) {
      const float mn = fmaxf(mi, pmax);
      const float a = __expf(mi - mn);
#pragma unroll
      for (int r = 0; r < 4; ++r) {
        const float ar = __shfl(a, quad * 4 + r);
#pragma unroll
        for (int nt = 0; nt < 4; ++nt) O[nt][r] *= ar;
      }
      li *= a;
      mi = mn;
    }

    float rs = 0.f;
#pragma unroll
    for (int nt = 0; nt < 4; ++nt)
#pragma unroll
      for (int r = 0; r < 4; ++r) {
        S[nt][r] = __expf(S[nt][r] - mi);
        rs += S[nt][r];
      }
    rs += __shfl_xor(rs, 16);
    rs += __shfl_xor(rs, 32);
    li += rs;

    // pack P -> bf16 and write lane's 4 runs of 4 consecutive k's (b64 each)
#pragma unroll
    for (int nt = 0; nt < 4; ++nt) {
      unsigned int u0, u1;
      asm("v_cvt_pk_bf16_f32 %0, %1, %2" : "=v"(u0) : "v"(S[nt][0]), "v"(S[nt][1]));
      asm("v_cvt_pk_bf16_f32 %0, %1, %2" : "=v"(u1) : "v"(S[nt][2]), "v"(S[nt][3]));
      const int kcb = nt * 2 + (quad >> 1);          // k>>3
      uint2 pk; pk.x = u0; pk.y = u1;
      *(uint2*)&Ps[(kcb * 64 + wr + ln) * 8 + (quad & 1) * 4] = pk;
    }

#pragma unroll
    for (int ks = 0; ks < 2; ++ks) {
      const short8 pf = *(const short8*)&Ps[((ks * 4 + quad) * 64 + wr + ln) * 8];
#pragma unroll
      for (int nt = 0; nt < 4; ++nt) {
        const short8 vf = *(const short8*)&Vs[cur][((ks * 4 + quad) * 64 + nt * 16 + ln) * 8];
        O[nt] = MFMA16(pf, vf, O[nt]);
      }
    }

#pragma unroll
    for (int nt = 0; nt < 4; ++nt) bm[nt] = bmn[nt];
    __syncthreads();  // V buffer handoff; drains next-tile staging
  }

#pragma unroll
  for (int r = 0; r < 4; ++r) {
    const float lr = __shfl(li, quad * 4 + r);
    const float inv = 1.0f / fmaxf(lr, 1e-6f);
    const int qg = q0 + wr + quad * 4 + r;
#pragma unroll
    for (int nt = 0; nt < 4; ++nt)
      ctx[((size_t)(b * Ss + qg)) * 1024 + h * 64 + nt * 16 + ln] =
          f2bf(O[nt][r] * inv);
  }
}

// ---- launch ----------------------------------------------------------------
extern "C" void kernel_launch(void* const* d_in, const int* in_sizes, int n_in,
                              void* d_out, int out_size, void* d_ws, size_t ws_size,
                              hipStream_t stream) {
  const float* query = (const float*)d_in[0];
  const float* key   = (const float*)d_in[1];
  const float* value = (const float*)d_in[2];
  const int*   kpm   = (const int*)d_in[3];
  const float* bias  = (const float*)d_in[4];
  const float* q_w   = (const float*)d_in[5];
  const float* q_b   = (const float*)d_in[6];
  const float* k_w   = (const float*)d_in[7];
  const float* k_b   = (const float*)d_in[8];
  const float* v_w   = (const float*)d_in[9];
  const float* v_b   = (const float*)d_in[10];
  const float* o_w   = (const float*)d_in[11];
  const float* o_b   = (const float*)d_in[12];
  float* out = (float*)d_out;

  char* ws = (char*)d_ws;
  const size_t MB = 1024 * 1024;
  u16* xq = (u16*)(ws + 0 * MB);
  u16* xk = (u16*)(ws + 8 * MB);
  u16* xv = (u16*)(ws + 16 * MB);
  u16* wq = (u16*)(ws + 24 * MB);
  u16* wk = (u16*)(ws + 26 * MB);
  u16* wv = (u16*)(ws + 28 * MB);
  u16* wo = (u16*)(ws + 30 * MB);
  u16* qb = (u16*)(ws + 32 * MB);
  u16* kb = (u16*)(ws + 40 * MB);
  u16* vb = (u16*)(ws + 48 * MB);
  u16* cx = (u16*)(ws + 56 * MB);
  u16* vt = (u16*)(ws + 0 * MB);     // alias xq (dead after gemm_qkv)

  prep<<<dim3(16384), 256, 0, stream>>>(query, key, value, q_w, k_w, v_w, o_w,
                                        xq, xk, xv, wq, wk, wv, wo);
  gemm_qkv<<<dim3(8, 32, 3), 256, 0, stream>>>(xq, xk, xv, wq, wk, wv,
                                               q_b, k_b, v_b, qb, kb, vb);
  transpose_v<<<dim3(32, 32), 256, 0, stream>>>(vb, vt);
  attn<<<dim3(32, 32), 256, 0, stream>>>(qb, kb, vt, bias, kpm, cx);
  gemm_o<<<dim3(8, 32), 256, 0, stream>>>(cx, wo, o_b, out);
}

// Round 6
// 625.856 us; speedup vs baseline: 1.0719x; 1.0719x over previous
//
#include <hip/hip_runtime.h>
#include <math.h>

// B=2, S=2048, H=1024, NH=16, HD=64
#define Ss  2048
#define Hh  1024

typedef unsigned short u16;
typedef __attribute__((ext_vector_type(8))) short short8;
typedef __attribute__((ext_vector_type(4))) float fx4;

__device__ __forceinline__ u16 f2bf(float f) {
  unsigned int u = __float_as_uint(f);
  u = (u + 0x7fffu + ((u >> 16) & 1u)) >> 16;
  return (u16)u;
}

__device__ __forceinline__ void gld_lds16(const u16* g, u16* l) {
  __builtin_amdgcn_global_load_lds(
      (const __attribute__((address_space(1))) unsigned int*)(const unsigned int*)g,
      (__attribute__((address_space(3))) unsigned int*)(unsigned int*)l, 16, 0, 0);
}

#define MFMA16(a,b,c) __builtin_amdgcn_mfma_f32_16x16x32_bf16((a),(b),(c),0,0,0)

// ---- fused prep: cast q/k/v (12288 blocks) + cast weights (4096 blocks) ----
__global__ __launch_bounds__(256) void prep(
    const float* __restrict__ q, const float* __restrict__ k,
    const float* __restrict__ v, const float* __restrict__ wq,
    const float* __restrict__ wk, const float* __restrict__ wv,
    const float* __restrict__ wo,
    u16* __restrict__ oq, u16* __restrict__ ok, u16* __restrict__ ov,
    u16* __restrict__ owq, u16* __restrict__ owk, u16* __restrict__ owv,
    u16* __restrict__ owo) {
  const int bid = blockIdx.x;
  const float* in; u16* out; int x;
  if (bid < 12288) {
    const int z = bid >> 12; x = bid & 4095;
    in = z == 0 ? q : (z == 1 ? k : v);
    out = z == 0 ? oq : (z == 1 ? ok : ov);
  } else {
    const int t = bid - 12288, z = t >> 10; x = t & 1023;
    in = z == 0 ? wq : (z == 1 ? wk : (z == 2 ? wv : wo));
    out = z == 0 ? owq : (z == 1 ? owk : (z == 2 ? owv : owo));
  }
  const int i = (x * 256 + threadIdx.x) * 4;
  const float4 vv = *(const float4*)(in + i);
  ushort4 r; r.x = f2bf(vv.x); r.y = f2bf(vv.y); r.z = f2bf(vv.z); r.w = f2bf(vv.w);
  *(ushort4*)(out + i) = r;
}

// ---- GEMM: C[M,N] = A[M,K]@W[N,K]^T + bias, 64x128 tile, BK=32 ------------
// Smaller tile -> 2x the blocks (gemm_qkv ~6/CU, gemm_o 2/CU) for TLP to hide
// staging latency. Per wave: 64x32 output (acc[4][2], 32 VGPR).
// Staging is wave-uniform 1KB gld_lds calls: wave w stages kc-plane w.
template <int MODE>
__device__ __forceinline__ void gemm_core(const u16* __restrict__ A,
    const u16* __restrict__ W, const float* __restrict__ bias,
    void* __restrict__ out, float scale) {
  __shared__ __align__(16) u16 As[2][2048];  // [kc 0..3][row 0..63]*8
  __shared__ __align__(16) u16 Bs[2][4096];  // [kc 0..3][row 0..127]*8
  const int tid = threadIdx.x;
  const int w = tid >> 6, lane = tid & 63, ln = lane & 15, quad = lane >> 4;
  const int i0 = blockIdx.y * 64, j0 = blockIdx.x * 128;
  const int wc = w * 32;
  fx4 acc[4][2] = {};
  const u16* sa  = A + (size_t)(i0 + lane) * 1024 + w * 8;        // kc=w, row=lane
  const u16* sb0 = W + (size_t)(j0 + lane) * 1024 + w * 8;        // kc=w, rows 0-63
  const u16* sb1 = W + (size_t)(j0 + 64 + lane) * 1024 + w * 8;   // kc=w, rows 64-127
  const int da = w * 512, db0 = w * 1024, db1 = w * 1024 + 512;

  // prologue: stage k-tile 0 into buffer 0
  gld_lds16(sa, &As[0][da]);
  gld_lds16(sb0, &Bs[0][db0]); gld_lds16(sb1, &Bs[0][db1]);
  __syncthreads();

  for (int k0 = 0; k0 < 1024; k0 += 32) {
    const int cur = (k0 >> 5) & 1;
    if (k0 + 32 < 1024) {
      const int nb = cur ^ 1;
      gld_lds16(sa + k0 + 32, &As[nb][da]);
      gld_lds16(sb0 + k0 + 32, &Bs[nb][db0]);
      gld_lds16(sb1 + k0 + 32, &Bs[nb][db1]);
    }
    short8 a[4], b[2];
#pragma unroll
    for (int t = 0; t < 4; ++t)
      a[t] = *(const short8*)&As[cur][(quad * 64 + t * 16 + ln) * 8];
#pragma unroll
    for (int n = 0; n < 2; ++n)
      b[n] = *(const short8*)&Bs[cur][(quad * 128 + wc + n * 16 + ln) * 8];
#pragma unroll
    for (int mt = 0; mt < 4; ++mt)
#pragma unroll
      for (int n = 0; n < 2; ++n)
        acc[mt][n] = MFMA16(a[mt], b[n], acc[mt][n]);
    __syncthreads();  // drains staging of next tile; protects buffer reuse
  }
#pragma unroll
  for (int n = 0; n < 2; ++n) {
    const int col = j0 + wc + n * 16 + ln;
    const float bv = bias[col];
#pragma unroll
    for (int mt = 0; mt < 4; ++mt)
#pragma unroll
      for (int r = 0; r < 4; ++r) {
        const int row = i0 + mt * 16 + quad * 4 + r;
        const float val = (acc[mt][n][r] + bv) * scale;
        if (MODE == 1) {
          const int bb = row >> 11, s = row & 2047, h = col >> 6, d = col & 63;
          ((u16*)out)[((size_t)(bb * 16 + h) * 2048 + s) * 64 + d] = f2bf(val);
        } else {
          ((float*)out)[(size_t)row * 1024 + col] = val;
        }
      }
  }
}

__global__ __launch_bounds__(256, 4) void gemm_qkv(
    const u16* xq, const u16* xk, const u16* xv,
    const u16* wq, const u16* wk, const u16* wv,
    const float* bq, const float* bk, const float* bv,
    u16* q, u16* k, u16* v) {
  const int z = blockIdx.z;
  const u16* A = z == 0 ? xq : (z == 1 ? xk : xv);
  const u16* W = z == 0 ? wq : (z == 1 ? wk : wv);
  const float* bb = z == 0 ? bq : (z == 1 ? bk : bv);
  u16* o = z == 0 ? q : (z == 1 ? k : v);
  const float sc = z == 0 ? 0.125f : 1.0f;
  gemm_core<1>(A, W, bb, o, sc);
}

__global__ __launch_bounds__(256, 4) void gemm_o(const u16* ctx, const u16* wo,
                                                 const float* ob, float* out) {
  gemm_core<0>(ctx, wo, ob, out, 1.0f);
}

// ---- V transpose: (bh,S,HD) -> (bh,HD,S), bf16 -----------------------------
__global__ __launch_bounds__(256) void transpose_v(const u16* __restrict__ v,
                                                   u16* __restrict__ vt) {
  __shared__ u16 T[64][72];
  const int tid = threadIdx.x;
  const int bh = blockIdx.y, s0 = blockIdx.x * 64;
#pragma unroll
  for (int i = 0; i < 2; ++i) {
    const int L = i * 256 + tid, key = L >> 3, dc = L & 7;
    const uint4 val = *(const uint4*)&v[((size_t)bh * 2048 + s0 + key) * 64 + dc * 8];
    *(uint4*)&T[key][dc * 8] = val;
  }
  __syncthreads();
#pragma unroll
  for (int i = 0; i < 2; ++i) {
    const int L = i * 256 + tid, d = L >> 3, kc = L & 7;
    u16 tmp[8];
#pragma unroll
    for (int j = 0; j < 8; ++j) tmp[j] = T[kc * 8 + j][d];
    *(uint4*)&vt[((size_t)bh * 64 + d) * 2048 + s0 + kc * 8] = *(const uint4*)tmp;
  }
}

// ---- flash attention: 64 q-rows/block (16/wave), 64-key tiles --------------
// Round-2 structure (best verified): K and V both LDS double-buffered via
// global_load_lds; swapped QK^T keeps softmax lane-local; cvt_pk P-pack;
// defer-max; mask read directly from kpm ints.
__global__ __launch_bounds__(256) void attn(const u16* __restrict__ Qb,
    const u16* __restrict__ Kb, const u16* __restrict__ VT,
    const float* __restrict__ bias, const int* __restrict__ kpm,
    u16* __restrict__ ctx) {
  __shared__ __align__(16) u16 Ks[2][4096];  // [c0..7][key0..63]*8
  __shared__ __align__(16) u16 Vs[2][4096];  // [kc0..7][d0..63]*8
  __shared__ __align__(16) u16 Ps[4096];     // [kc0..7][q0..63]*8 (wave-private rows)
  const int tid = threadIdx.x;
  const int w = tid >> 6, lane = tid & 63, ln = lane & 15, quad = lane >> 4;
  const int q0 = blockIdx.x * 64;
  const int hb = blockIdx.y, h = hb >> 1, b = hb & 1, bh = b * 16 + h;
  const int wr = w * 16;            // wave's 16 q-rows within tile

  short8 qf[2];                      // B-frag: col = q = wr+ln, c = ks*32+quad*8
#pragma unroll
  for (int ks = 0; ks < 2; ++ks)
    qf[ks] = *(const short8*)&Qb[((size_t)bh * 2048 + q0 + wr + ln) * 64 +
                                 ks * 32 + quad * 8];
  float mi = -3.0e38f, li = 0.f;     // per-lane: q = q0+wr+ln
  fx4 O[4] = {};                     // O[nt][r]: q = quad*4+r, d = nt*16+ln

  const int L0 = w * 64 + lane, L1 = L0 + 256;
  const u16* sk0 = Kb + ((size_t)bh * 2048 + (L0 & 63)) * 64 + (L0 >> 6) * 8;
  const u16* sk1 = Kb + ((size_t)bh * 2048 + (L1 & 63)) * 64 + (L1 >> 6) * 8;
  const u16* sv0 = VT + ((size_t)bh * 64 + (L0 & 63)) * 2048 + (L0 >> 6) * 8;
  const u16* sv1 = VT + ((size_t)bh * 64 + (L1 & 63)) * 2048 + (L1 >> 6) * 8;
  const int d0 = (w * 64) * 8, d1 = (256 + w * 64) * 8;

  // per-lane bias base: row q = q0+wr+ln, cols kt + nt*16 + quad*4 (+0..3)
  const float* bp = bias + (size_t)h * Ss * Ss + (size_t)(q0 + wr + ln) * Ss + quad * 4;
  const int* mp = kpm + b * Ss + quad * 4;

  // prologue: stage K/V tile 0 into buffer 0; bias+mask for tile 0
  gld_lds16(sk0, &Ks[0][d0]); gld_lds16(sk1, &Ks[0][d1]);
  gld_lds16(sv0, &Vs[0][d0]); gld_lds16(sv1, &Vs[0][d1]);
  fx4 bm[4];
#pragma unroll
  for (int nt = 0; nt < 4; ++nt) {
    const float4 bv = *(const float4*)(bp + nt * 16);
    const int4 mv = *(const int4*)(mp + nt * 16);
    bm[nt][0] = bv.x + (mv.x ? -1.0e30f : 0.0f);
    bm[nt][1] = bv.y + (mv.y ? -1.0e30f : 0.0f);
    bm[nt][2] = bv.z + (mv.z ? -1.0e30f : 0.0f);
    bm[nt][3] = bv.w + (mv.w ? -1.0e30f : 0.0f);
  }
  __syncthreads();

  for (int kt = 0; kt < Ss; kt += 64) {
    const int cur = (kt >> 6) & 1;
    if (kt + 64 < Ss) {
      const int nb = cur ^ 1;
      gld_lds16(sk0 + (size_t)(kt + 64) * 64, &Ks[nb][d0]);
      gld_lds16(sk1 + (size_t)(kt + 64) * 64, &Ks[nb][d1]);
      gld_lds16(sv0 + kt + 64, &Vs[nb][d0]);
      gld_lds16(sv1 + kt + 64, &Vs[nb][d1]);
    }
    const int kn = (kt + 64 < Ss) ? kt + 64 : kt;
    fx4 bmn[4];
#pragma unroll
    for (int nt = 0; nt < 4; ++nt) {
      const float4 bv = *(const float4*)(bp + kn + nt * 16);
      const int4 mv = *(const int4*)(mp + kn + nt * 16);
      bmn[nt][0] = bv.x + (mv.x ? -1.0e30f : 0.0f);
      bmn[nt][1] = bv.y + (mv.y ? -1.0e30f : 0.0f);
      bmn[nt][2] = bv.z + (mv.z ? -1.0e30f : 0.0f);
      bmn[nt][3] = bv.w + (mv.w ? -1.0e30f : 0.0f);
    }

    // S'[k][q] = K*Q: lane holds k = kt + nt*16 + quad*4 + r, q = q0+wr+ln
    fx4 S[4] = {};
#pragma unroll
    for (int ks = 0; ks < 2; ++ks)
#pragma unroll
      for (int nt = 0; nt < 4; ++nt) {
        const short8 kf = *(const short8*)&Ks[cur][((ks * 4 + quad) * 64 + nt * 16 + ln) * 8];
        S[nt] = MFMA16(kf, qf[ks], S[nt]);
      }

    // lane-local softmax over the lane's 16 scores
    float pmax = -3.0e38f;
#pragma unroll
    for (int nt = 0; nt < 4; ++nt)
#pragma unroll
      for (int r = 0; r < 4; ++r) {
        S[nt][r] += bm[nt][r];
        pmax = fmaxf(pmax, S[nt][r]);
      }
    pmax = fmaxf(pmax, __shfl_xor(pmax, 16));
    pmax = fmaxf(pmax, __shfl_xor(pmax, 32));

    // defer-max: only rescale when the running max grew by > 8
    if (!__all(pmax <= mi + 8.0f)) {
      const float mn = fmaxf(mi, pmax);
      const float a = __expf(mi - mn);
#pragma unroll
      for (int r = 0; r < 4; ++r) {
        const float ar = __shfl(a, quad * 4 + r);
#pragma unroll
        for (int nt = 0; nt < 4; ++nt) O[nt][r] *= ar;
      }
      li *= a;
      mi = mn;
    }

    float rs = 0.f;
#pragma unroll
    for (int nt = 0; nt < 4; ++nt)
#pragma unroll
      for (int r = 0; r < 4; ++r) {
        S[nt][r] = __expf(S[nt][r] - mi);
        rs += S[nt][r];
      }
    rs += __shfl_xor(rs, 16);
    rs += __shfl_xor(rs, 32);
    li += rs;

    // pack P -> bf16 and write lane's 4 runs of 4 consecutive k's (b64 each)
#pragma unroll
    for (int nt = 0; nt < 4; ++nt) {
      unsigned int u0, u1;
      asm("v_cvt_pk_bf16_f32 %0, %1, %2" : "=v"(u0) : "v"(S[nt][0]), "v"(S[nt][1]));
      asm("v_cvt_pk_bf16_f32 %0, %1, %2" : "=v"(u1) : "v"(S[nt][2]), "v"(S[nt][3]));
      const int kcb = nt * 2 + (quad >> 1);          // k>>3
      uint2 pk; pk.x = u0; pk.y = u1;
      *(uint2*)&Ps[(kcb * 64 + wr + ln) * 8 + (quad & 1) * 4] = pk;
    }

#pragma unroll
    for (int ks = 0; ks < 2; ++ks) {
      const short8 pf = *(const short8*)&Ps[((ks * 4 + quad) * 64 + wr + ln) * 8];
#pragma unroll
      for (int nt = 0; nt < 4; ++nt) {
        const short8 vf = *(const short8*)&Vs[cur][((ks * 4 + quad) * 64 + nt * 16 + ln) * 8];
        O[nt] = MFMA16(pf, vf, O[nt]);
      }
    }

#pragma unroll
    for (int nt = 0; nt < 4; ++nt) bm[nt] = bmn[nt];
    __syncthreads();  // buffer handoff; drains next-tile staging
  }

#pragma unroll
  for (int r = 0; r < 4; ++r) {
    const float lr = __shfl(li, quad * 4 + r);
    const float inv = 1.0f / fmaxf(lr, 1e-6f);
    const int qg = q0 + wr + quad * 4 + r;
#pragma unroll
    for (int nt = 0; nt < 4; ++nt)
      ctx[((size_t)(b * Ss + qg)) * 1024 + h * 64 + nt * 16 + ln] =
          f2bf(O[nt][r] * inv);
  }
}

// ---- launch ----------------------------------------------------------------
extern "C" void kernel_launch(void* const* d_in, const int* in_sizes, int n_in,
                              void* d_out, int out_size, void* d_ws, size_t ws_size,
                              hipStream_t stream) {
  const float* query = (const float*)d_in[0];
  const float* key   = (const float*)d_in[1];
  const float* value = (const float*)d_in[2];
  const int*   kpm   = (const int*)d_in[3];
  const float* bias  = (const float*)d_in[4];
  const float* q_w   = (const float*)d_in[5];
  const float* q_b   = (const float*)d_in[6];
  const float* k_w   = (const float*)d_in[7];
  const float* k_b   = (const float*)d_in[8];
  const float* v_w   = (const float*)d_in[9];
  const float* v_b   = (const float*)d_in[10];
  const float* o_w   = (const float*)d_in[11];
  const float* o_b   = (const float*)d_in[12];
  float* out = (float*)d_out;

  char* ws = (char*)d_ws;
  const size_t MB = 1024 * 1024;
  u16* xq = (u16*)(ws + 0 * MB);
  u16* xk = (u16*)(ws + 8 * MB);
  u16* xv = (u16*)(ws + 16 * MB);
  u16* wq = (u16*)(ws + 24 * MB);
  u16* wk = (u16*)(ws + 26 * MB);
  u16* wv = (u16*)(ws + 28 * MB);
  u16* wo = (u16*)(ws + 30 * MB);
  u16* qb = (u16*)(ws + 32 * MB);
  u16* kb = (u16*)(ws + 40 * MB);
  u16* vb = (u16*)(ws + 48 * MB);
  u16* cx = (u16*)(ws + 56 * MB);
  u16* vt = (u16*)(ws + 0 * MB);     // alias xq (dead after gemm_qkv)

  prep<<<dim3(16384), 256, 0, stream>>>(query, key, value, q_w, k_w, v_w, o_w,
                                        xq, xk, xv, wq, wk, wv, wo);
  gemm_qkv<<<dim3(8, 64, 3), 256, 0, stream>>>(xq, xk, xv, wq, wk, wv,
                                               q_b, k_b, v_b, qb, kb, vb);
  transpose_v<<<dim3(32, 32), 256, 0, stream>>>(vb, vt);
  attn<<<dim3(32, 32), 256, 0, stream>>>(qb, kb, vt, bias, kpm, cx);
  gemm_o<<<dim3(8, 64), 256, 0, stream>>>(cx, wo, o_b, out);
}

// Round 7
// 610.844 us; speedup vs baseline: 1.0983x; 1.0246x over previous
//
#include <hip/hip_runtime.h>
#include <math.h>

// B=2, S=2048, H=1024, NH=16, HD=64
#define Ss  2048
#define Hh  1024

typedef unsigned short u16;
typedef __attribute__((ext_vector_type(8))) short short8;
typedef __attribute__((ext_vector_type(4))) float fx4;

__device__ __forceinline__ u16 f2bf(float f) {
  unsigned int u = __float_as_uint(f);
  u = (u + 0x7fffu + ((u >> 16) & 1u)) >> 16;
  return (u16)u;
}

__device__ __forceinline__ void gld_lds16(const u16* g, u16* l) {
  __builtin_amdgcn_global_load_lds(
      (const __attribute__((address_space(1))) unsigned int*)(const unsigned int*)g,
      (__attribute__((address_space(3))) unsigned int*)(unsigned int*)l, 16, 0, 0);
}

#define MFMA16(a,b,c) __builtin_amdgcn_mfma_f32_16x16x32_bf16((a),(b),(c),0,0,0)

// ---- fused prep: cast q/k/v (12288 blocks) + cast weights (4096 blocks) ----
__global__ __launch_bounds__(256) void prep(
    const float* __restrict__ q, const float* __restrict__ k,
    const float* __restrict__ v, const float* __restrict__ wq,
    const float* __restrict__ wk, const float* __restrict__ wv,
    const float* __restrict__ wo,
    u16* __restrict__ oq, u16* __restrict__ ok, u16* __restrict__ ov,
    u16* __restrict__ owq, u16* __restrict__ owk, u16* __restrict__ owv,
    u16* __restrict__ owo) {
  const int bid = blockIdx.x;
  const float* in; u16* out; int x;
  if (bid < 12288) {
    const int z = bid >> 12; x = bid & 4095;
    in = z == 0 ? q : (z == 1 ? k : v);
    out = z == 0 ? oq : (z == 1 ? ok : ov);
  } else {
    const int t = bid - 12288, z = t >> 10; x = t & 1023;
    in = z == 0 ? wq : (z == 1 ? wk : (z == 2 ? wv : wo));
    out = z == 0 ? owq : (z == 1 ? owk : (z == 2 ? owv : owo));
  }
  const int i = (x * 256 + threadIdx.x) * 4;
  const float4 vv = *(const float4*)(in + i);
  ushort4 r; r.x = f2bf(vv.x); r.y = f2bf(vv.y); r.z = f2bf(vv.z); r.w = f2bf(vv.w);
  *(ushort4*)(out + i) = r;
}

// ---- GEMM: C[M,N] = A[M,K]@W[N,K]^T + bias, K=N=1024, 128x128 tile --------
// (round-2 verified version: double-buffered gld_lds staging, 16 MFMA/step)
template <int MODE>
__device__ __forceinline__ void gemm_core(const u16* __restrict__ A,
    const u16* __restrict__ W, const float* __restrict__ bias,
    void* __restrict__ out, float scale) {
  __shared__ __align__(16) u16 As[2][4096];
  __shared__ __align__(16) u16 Bs[2][4096];
  const int tid = threadIdx.x;
  const int w = tid >> 6, lane = tid & 63, ln = lane & 15, quad = lane >> 4;
  const int i0 = blockIdx.y * 128, j0 = blockIdx.x * 128;
  const int wr = (w & 1) * 64, wc = (w >> 1) * 64;
  fx4 acc[4][4] = {};
  const int L0 = w * 64 + lane, L1 = L0 + 256;
  const u16* sa0 = A + (size_t)(i0 + (L0 & 127)) * 1024 + (L0 >> 7) * 8;
  const u16* sa1 = A + (size_t)(i0 + (L1 & 127)) * 1024 + (L1 >> 7) * 8;
  const u16* sb0 = W + (size_t)(j0 + (L0 & 127)) * 1024 + (L0 >> 7) * 8;
  const u16* sb1 = W + (size_t)(j0 + (L1 & 127)) * 1024 + (L1 >> 7) * 8;
  const int d0 = (w * 64) * 8, d1 = (256 + w * 64) * 8;

  gld_lds16(sa0, &As[0][d0]); gld_lds16(sa1, &As[0][d1]);
  gld_lds16(sb0, &Bs[0][d0]); gld_lds16(sb1, &Bs[0][d1]);
  __syncthreads();

  for (int k0 = 0; k0 < 1024; k0 += 32) {
    const int cur = (k0 >> 5) & 1;
    if (k0 + 32 < 1024) {
      const int nb = cur ^ 1;
      gld_lds16(sa0 + k0 + 32, &As[nb][d0]); gld_lds16(sa1 + k0 + 32, &As[nb][d1]);
      gld_lds16(sb0 + k0 + 32, &Bs[nb][d0]); gld_lds16(sb1 + k0 + 32, &Bs[nb][d1]);
    }
    short8 a[4], b[4];
#pragma unroll
    for (int t = 0; t < 4; ++t) {
      a[t] = *(const short8*)&As[cur][(quad * 128 + wr + t * 16 + ln) * 8];
      b[t] = *(const short8*)&Bs[cur][(quad * 128 + wc + t * 16 + ln) * 8];
    }
#pragma unroll
    for (int mt = 0; mt < 4; ++mt)
#pragma unroll
      for (int nt = 0; nt < 4; ++nt)
        acc[mt][nt] = MFMA16(a[mt], b[nt], acc[mt][nt]);
    __syncthreads();
  }
#pragma unroll
  for (int nt = 0; nt < 4; ++nt) {
    const int col = j0 + wc + nt * 16 + ln;
    const float bv = bias[col];
#pragma unroll
    for (int mt = 0; mt < 4; ++mt)
#pragma unroll
      for (int r = 0; r < 4; ++r) {
        const int row = i0 + wr + mt * 16 + quad * 4 + r;
        const float val = (acc[mt][nt][r] + bv) * scale;
        if (MODE == 1) {
          const int bb = row >> 11, s = row & 2047, h = col >> 6, d = col & 63;
          ((u16*)out)[((size_t)(bb * 16 + h) * 2048 + s) * 64 + d] = f2bf(val);
        } else {
          ((float*)out)[(size_t)row * 1024 + col] = val;
        }
      }
  }
}

__global__ __launch_bounds__(256) void gemm_qkv(
    const u16* xq, const u16* xk, const u16* xv,
    const u16* wq, const u16* wk, const u16* wv,
    const float* bq, const float* bk, const float* bv,
    u16* q, u16* k, u16* v) {
  const int z = blockIdx.z;
  const u16* A = z == 0 ? xq : (z == 1 ? xk : xv);
  const u16* W = z == 0 ? wq : (z == 1 ? wk : wv);
  const float* bb = z == 0 ? bq : (z == 1 ? bk : bv);
  u16* o = z == 0 ? q : (z == 1 ? k : v);
  const float sc = z == 0 ? 0.125f : 1.0f;
  gemm_core<1>(A, W, bb, o, sc);
}

__global__ __launch_bounds__(256) void gemm_o(const u16* ctx, const u16* wo,
                                              const float* ob, float* out) {
  gemm_core<0>(ctx, wo, ob, out, 1.0f);
}

// ---- V transpose: (bh,S,HD) -> (bh,HD,S), bf16 -----------------------------
__global__ __launch_bounds__(256) void transpose_v(const u16* __restrict__ v,
                                                   u16* __restrict__ vt) {
  __shared__ u16 T[64][72];
  const int tid = threadIdx.x;
  const int bh = blockIdx.y, s0 = blockIdx.x * 64;
#pragma unroll
  for (int i = 0; i < 2; ++i) {
    const int L = i * 256 + tid, key = L >> 3, dc = L & 7;
    const uint4 val = *(const uint4*)&v[((size_t)bh * 2048 + s0 + key) * 64 + dc * 8];
    *(uint4*)&T[key][dc * 8] = val;
  }
  __syncthreads();
#pragma unroll
  for (int i = 0; i < 2; ++i) {
    const int L = i * 256 + tid, d = L >> 3, kc = L & 7;
    u16 tmp[8];
#pragma unroll
    for (int j = 0; j < 8; ++j) tmp[j] = T[kc * 8 + j][d];
    *(uint4*)&vt[((size_t)bh * 64 + d) * 2048 + s0 + kc * 8] = *(const uint4*)tmp;
  }
}

// ---- flash attention: 128 q-rows/block, 8 waves (16 q/wave), 64-key tiles --
// Same per-wave math as round-2 best; 2x q-rows/block amortizes K/V staging
// and doubles waves/CU (24 @ 48KB LDS) so bias streaming + barrier drains are
// covered. Waves 0-3 stage K planes, waves 4-7 stage V planes.
__global__ __launch_bounds__(512) void attn(const u16* __restrict__ Qb,
    const u16* __restrict__ Kb, const u16* __restrict__ VT,
    const float* __restrict__ bias, const int* __restrict__ kpm,
    u16* __restrict__ ctx) {
  __shared__ __align__(16) u16 Ks[2][4096];  // [c0..7][key0..63]*8
  __shared__ __align__(16) u16 Vs[2][4096];  // [kc0..7][d0..63]*8
  __shared__ __align__(16) u16 Ps[8192];     // [kc0..7][q0..127]*8 (wave-private rows)
  const int tid = threadIdx.x;
  const int w = tid >> 6, lane = tid & 63, ln = lane & 15, quad = lane >> 4;
  const int q0 = blockIdx.x * 128;
  const int hb = blockIdx.y, h = hb >> 1, b = hb & 1, bh = b * 16 + h;
  const int wr = w * 16;            // wave's 16 q-rows within the 128-row tile

  short8 qf[2];                      // B-frag: col = q = wr+ln, c = ks*32+quad*8
#pragma unroll
  for (int ks = 0; ks < 2; ++ks)
    qf[ks] = *(const short8*)&Qb[((size_t)bh * 2048 + q0 + wr + ln) * 64 +
                                 ks * 32 + quad * 8];
  float mi = -3.0e38f, li = 0.f;     // per-lane: q = q0+wr+ln
  fx4 O[4] = {};                     // O[nt][r]: q = quad*4+r, d = nt*16+ln

  // staging role: waves 0-3 stage K (c-planes), waves 4-7 stage V (kc-planes)
  const int wk = w & 3;
  const u16* s0, *s1;
  if (w < 4) {   // K: key = lane, c-chunk = wk / wk+4 ; advance by kt*64
    s0 = Kb + ((size_t)bh * 2048 + lane) * 64 + wk * 8;
    s1 = Kb + ((size_t)bh * 2048 + lane) * 64 + (wk + 4) * 8;
  } else {       // V: d = lane, key-chunk = wk / wk+4 ; advance by kt
    s0 = VT + ((size_t)bh * 64 + lane) * 2048 + wk * 8;
    s1 = VT + ((size_t)bh * 64 + lane) * 2048 + (wk + 4) * 8;
  }
  const int dA0 = wk * 512, dA1 = 2048 + wk * 512;

  // per-lane bias base: row q = q0+wr+ln, cols kt + nt*16 + quad*4 (+0..3)
  const float* bp = bias + (size_t)h * Ss * Ss + (size_t)(q0 + wr + ln) * Ss + quad * 4;
  const int* mp = kpm + b * Ss + quad * 4;

  // prologue: stage K/V tile 0 into buffer 0; bias+mask for tile 0
  if (w < 4) { gld_lds16(s0, &Ks[0][dA0]); gld_lds16(s1, &Ks[0][dA1]); }
  else       { gld_lds16(s0, &Vs[0][dA0]); gld_lds16(s1, &Vs[0][dA1]); }
  fx4 bm[4];
#pragma unroll
  for (int nt = 0; nt < 4; ++nt) {
    const float4 bv = *(const float4*)(bp + nt * 16);
    const int4 mv = *(const int4*)(mp + nt * 16);
    bm[nt][0] = bv.x + (mv.x ? -1.0e30f : 0.0f);
    bm[nt][1] = bv.y + (mv.y ? -1.0e30f : 0.0f);
    bm[nt][2] = bv.z + (mv.z ? -1.0e30f : 0.0f);
    bm[nt][3] = bv.w + (mv.w ? -1.0e30f : 0.0f);
  }
  __syncthreads();

  for (int kt = 0; kt < Ss; kt += 64) {
    const int cur = (kt >> 6) & 1;
    if (kt + 64 < Ss) {
      const int nb = cur ^ 1;
      if (w < 4) {
        gld_lds16(s0 + (size_t)(kt + 64) * 64, &Ks[nb][dA0]);
        gld_lds16(s1 + (size_t)(kt + 64) * 64, &Ks[nb][dA1]);
      } else {
        gld_lds16(s0 + kt + 64, &Vs[nb][dA0]);
        gld_lds16(s1 + kt + 64, &Vs[nb][dA1]);
      }
    }
    const int kn = (kt + 64 < Ss) ? kt + 64 : kt;
    fx4 bmn[4];
#pragma unroll
    for (int nt = 0; nt < 4; ++nt) {
      const float4 bv = *(const float4*)(bp + kn + nt * 16);
      const int4 mv = *(const int4*)(mp + kn + nt * 16);
      bmn[nt][0] = bv.x + (mv.x ? -1.0e30f : 0.0f);
      bmn[nt][1] = bv.y + (mv.y ? -1.0e30f : 0.0f);
      bmn[nt][2] = bv.z + (mv.z ? -1.0e30f : 0.0f);
      bmn[nt][3] = bv.w + (mv.w ? -1.0e30f : 0.0f);
    }

    // S'[k][q] = K*Q: lane holds k = kt + nt*16 + quad*4 + r, q = q0+wr+ln
    fx4 S[4] = {};
#pragma unroll
    for (int ks = 0; ks < 2; ++ks)
#pragma unroll
      for (int nt = 0; nt < 4; ++nt) {
        const short8 kf = *(const short8*)&Ks[cur][((ks * 4 + quad) * 64 + nt * 16 + ln) * 8];
        S[nt] = MFMA16(kf, qf[ks], S[nt]);
      }

    // lane-local softmax over the lane's 16 scores
    float pmax = -3.0e38f;
#pragma unroll
    for (int nt = 0; nt < 4; ++nt)
#pragma unroll
      for (int r = 0; r < 4; ++r) {
        S[nt][r] += bm[nt][r];
        pmax = fmaxf(pmax, S[nt][r]);
      }
    pmax = fmaxf(pmax, __shfl_xor(pmax, 16));
    pmax = fmaxf(pmax, __shfl_xor(pmax, 32));

    // defer-max: only rescale when the running max grew by > 8
    if (!__all(pmax <= mi + 8.0f)) {
      const float mn = fmaxf(mi, pmax);
      const float a = __expf(mi - mn);
#pragma unroll
      for (int r = 0; r < 4; ++r) {
        const float ar = __shfl(a, quad * 4 + r);
#pragma unroll
        for (int nt = 0; nt < 4; ++nt) O[nt][r] *= ar;
      }
      li *= a;
      mi = mn;
    }

    float rs = 0.f;
#pragma unroll
    for (int nt = 0; nt < 4; ++nt)
#pragma unroll
      for (int r = 0; r < 4; ++r) {
        S[nt][r] = __expf(S[nt][r] - mi);
        rs += S[nt][r];
      }
    rs += __shfl_xor(rs, 16);
    rs += __shfl_xor(rs, 32);
    li += rs;

    // pack P -> bf16 and write lane's 4 runs of 4 consecutive k's (b64 each)
#pragma unroll
    for (int nt = 0; nt < 4; ++nt) {
      unsigned int u0, u1;
      asm("v_cvt_pk_bf16_f32 %0, %1, %2" : "=v"(u0) : "v"(S[nt][0]), "v"(S[nt][1]));
      asm("v_cvt_pk_bf16_f32 %0, %1, %2" : "=v"(u1) : "v"(S[nt][2]), "v"(S[nt][3]));
      const int kcb = nt * 2 + (quad >> 1);          // k>>3
      uint2 pk; pk.x = u0; pk.y = u1;
      *(uint2*)&Ps[(kcb * 128 + wr + ln) * 8 + (quad & 1) * 4] = pk;
    }

#pragma unroll
    for (int ks = 0; ks < 2; ++ks) {
      const short8 pf = *(const short8*)&Ps[((ks * 4 + quad) * 128 + wr + ln) * 8];
#pragma unroll
      for (int nt = 0; nt < 4; ++nt) {
        const short8 vf = *(const short8*)&Vs[cur][((ks * 4 + quad) * 64 + nt * 16 + ln) * 8];
        O[nt] = MFMA16(pf, vf, O[nt]);
      }
    }

#pragma unroll
    for (int nt = 0; nt < 4; ++nt) bm[nt] = bmn[nt];
    __syncthreads();  // buffer handoff; drains next-tile staging
  }

#pragma unroll
  for (int r = 0; r < 4; ++r) {
    const float lr = __shfl(li, quad * 4 + r);
    const float inv = 1.0f / fmaxf(lr, 1e-6f);
    const int qg = q0 + wr + quad * 4 + r;
#pragma unroll
    for (int nt = 0; nt < 4; ++nt)
      ctx[((size_t)(b * Ss + qg)) * 1024 + h * 64 + nt * 16 + ln] =
          f2bf(O[nt][r] * inv);
  }
}

// ---- launch ----------------------------------------------------------------
extern "C" void kernel_launch(void* const* d_in, const int* in_sizes, int n_in,
                              void* d_out, int out_size, void* d_ws, size_t ws_size,
                              hipStream_t stream) {
  const float* query = (const float*)d_in[0];
  const float* key   = (const float*)d_in[1];
  const float* value = (const float*)d_in[2];
  const int*   kpm   = (const int*)d_in[3];
  const float* bias  = (const float*)d_in[4];
  const float* q_w   = (const float*)d_in[5];
  const float* q_b   = (const float*)d_in[6];
  const float* k_w   = (const float*)d_in[7];
  const float* k_b   = (const float*)d_in[8];
  const float* v_w   = (const float*)d_in[9];
  const float* v_b   = (const float*)d_in[10];
  const float* o_w   = (const float*)d_in[11];
  const float* o_b   = (const float*)d_in[12];
  float* out = (float*)d_out;

  char* ws = (char*)d_ws;
  const size_t MB = 1024 * 1024;
  u16* xq = (u16*)(ws + 0 * MB);
  u16* xk = (u16*)(ws + 8 * MB);
  u16* xv = (u16*)(ws + 16 * MB);
  u16* wq = (u16*)(ws + 24 * MB);
  u16* wk = (u16*)(ws + 26 * MB);
  u16* wv = (u16*)(ws + 28 * MB);
  u16* wo = (u16*)(ws + 30 * MB);
  u16* qb = (u16*)(ws + 32 * MB);
  u16* kb = (u16*)(ws + 40 * MB);
  u16* vb = (u16*)(ws + 48 * MB);
  u16* cx = (u16*)(ws + 56 * MB);
  u16* vt = (u16*)(ws + 0 * MB);     // alias xq (dead after gemm_qkv)

  prep<<<dim3(16384), 256, 0, stream>>>(query, key, value, q_w, k_w, v_w, o_w,
                                        xq, xk, xv, wq, wk, wv, wo);
  gemm_qkv<<<dim3(8, 32, 3), 256, 0, stream>>>(xq, xk, xv, wq, wk, wv,
                                               q_b, k_b, v_b, qb, kb, vb);
  transpose_v<<<dim3(32, 32), 256, 0, stream>>>(vb, vt);
  attn<<<dim3(16, 32), 512, 0, stream>>>(qb, kb, vt, bias, kpm, cx);
  gemm_o<<<dim3(8, 32), 256, 0, stream>>>(cx, wo, o_b, out);
}

// Round 8
// 595.454 us; speedup vs baseline: 1.1267x; 1.0258x over previous
//
#include <hip/hip_runtime.h>
#include <math.h>

// B=2, S=2048, H=1024, NH=16, HD=64
#define Ss  2048
#define Hh  1024

typedef unsigned short u16;
typedef __attribute__((ext_vector_type(8))) short short8;
typedef __attribute__((ext_vector_type(4))) float fx4;

__device__ __forceinline__ u16 f2bf(float f) {
  unsigned int u = __float_as_uint(f);
  u = (u + 0x7fffu + ((u >> 16) & 1u)) >> 16;
  return (u16)u;
}

__device__ __forceinline__ void gld_lds16(const u16* g, u16* l) {
  __builtin_amdgcn_global_load_lds(
      (const __attribute__((address_space(1))) unsigned int*)(const unsigned int*)g,
      (__attribute__((address_space(3))) unsigned int*)(unsigned int*)l, 16, 0, 0);
}

#define MFMA16(a,b,c) __builtin_amdgcn_mfma_f32_16x16x32_bf16((a),(b),(c),0,0,0)

// ---- fused prep: cast q/k/v (12288 blocks) + cast weights (4096 blocks) ----
__global__ __launch_bounds__(256) void prep(
    const float* __restrict__ q, const float* __restrict__ k,
    const float* __restrict__ v, const float* __restrict__ wq,
    const float* __restrict__ wk, const float* __restrict__ wv,
    const float* __restrict__ wo,
    u16* __restrict__ oq, u16* __restrict__ ok, u16* __restrict__ ov,
    u16* __restrict__ owq, u16* __restrict__ owk, u16* __restrict__ owv,
    u16* __restrict__ owo) {
  const int bid = blockIdx.x;
  const float* in; u16* out; int x;
  if (bid < 12288) {
    const int z = bid >> 12; x = bid & 4095;
    in = z == 0 ? q : (z == 1 ? k : v);
    out = z == 0 ? oq : (z == 1 ? ok : ov);
  } else {
    const int t = bid - 12288, z = t >> 10; x = t & 1023;
    in = z == 0 ? wq : (z == 1 ? wk : (z == 2 ? wv : wo));
    out = z == 0 ? owq : (z == 1 ? owk : (z == 2 ? owv : owo));
  }
  const int i = (x * 256 + threadIdx.x) * 4;
  const float4 vv = *(const float4*)(in + i);
  ushort4 r; r.x = f2bf(vv.x); r.y = f2bf(vv.y); r.z = f2bf(vv.z); r.w = f2bf(vv.w);
  *(ushort4*)(out + i) = r;
}

// ---- GEMM: C[M,N] = A[M,K]@W[N,K]^T + bias, K=N=1024, 128x128 tile --------
// (round-2 verified version: double-buffered gld_lds staging, 16 MFMA/step)
template <int MODE>
__device__ __forceinline__ void gemm_core(const u16* __restrict__ A,
    const u16* __restrict__ W, const float* __restrict__ bias,
    void* __restrict__ out, float scale) {
  __shared__ __align__(16) u16 As[2][4096];
  __shared__ __align__(16) u16 Bs[2][4096];
  const int tid = threadIdx.x;
  const int w = tid >> 6, lane = tid & 63, ln = lane & 15, quad = lane >> 4;
  const int i0 = blockIdx.y * 128, j0 = blockIdx.x * 128;
  const int wr = (w & 1) * 64, wc = (w >> 1) * 64;
  fx4 acc[4][4] = {};
  const int L0 = w * 64 + lane, L1 = L0 + 256;
  const u16* sa0 = A + (size_t)(i0 + (L0 & 127)) * 1024 + (L0 >> 7) * 8;
  const u16* sa1 = A + (size_t)(i0 + (L1 & 127)) * 1024 + (L1 >> 7) * 8;
  const u16* sb0 = W + (size_t)(j0 + (L0 & 127)) * 1024 + (L0 >> 7) * 8;
  const u16* sb1 = W + (size_t)(j0 + (L1 & 127)) * 1024 + (L1 >> 7) * 8;
  const int d0 = (w * 64) * 8, d1 = (256 + w * 64) * 8;

  gld_lds16(sa0, &As[0][d0]); gld_lds16(sa1, &As[0][d1]);
  gld_lds16(sb0, &Bs[0][d0]); gld_lds16(sb1, &Bs[0][d1]);
  __syncthreads();

  for (int k0 = 0; k0 < 1024; k0 += 32) {
    const int cur = (k0 >> 5) & 1;
    if (k0 + 32 < 1024) {
      const int nb = cur ^ 1;
      gld_lds16(sa0 + k0 + 32, &As[nb][d0]); gld_lds16(sa1 + k0 + 32, &As[nb][d1]);
      gld_lds16(sb0 + k0 + 32, &Bs[nb][d0]); gld_lds16(sb1 + k0 + 32, &Bs[nb][d1]);
    }
    short8 a[4], b[4];
#pragma unroll
    for (int t = 0; t < 4; ++t) {
      a[t] = *(const short8*)&As[cur][(quad * 128 + wr + t * 16 + ln) * 8];
      b[t] = *(const short8*)&Bs[cur][(quad * 128 + wc + t * 16 + ln) * 8];
    }
#pragma unroll
    for (int mt = 0; mt < 4; ++mt)
#pragma unroll
      for (int nt = 0; nt < 4; ++nt)
        acc[mt][nt] = MFMA16(a[mt], b[nt], acc[mt][nt]);
    __syncthreads();
  }
#pragma unroll
  for (int nt = 0; nt < 4; ++nt) {
    const int col = j0 + wc + nt * 16 + ln;
    const float bv = bias[col];
#pragma unroll
    for (int mt = 0; mt < 4; ++mt)
#pragma unroll
      for (int r = 0; r < 4; ++r) {
        const int row = i0 + wr + mt * 16 + quad * 4 + r;
        const float val = (acc[mt][nt][r] + bv) * scale;
        if (MODE == 1) {
          const int bb = row >> 11, s = row & 2047, h = col >> 6, d = col & 63;
          ((u16*)out)[((size_t)(bb * 16 + h) * 2048 + s) * 64 + d] = f2bf(val);
        } else {
          ((float*)out)[(size_t)row * 1024 + col] = val;
        }
      }
  }
}

__global__ __launch_bounds__(256) void gemm_qkv(
    const u16* xq, const u16* xk, const u16* xv,
    const u16* wq, const u16* wk, const u16* wv,
    const float* bq, const float* bk, const float* bv,
    u16* q, u16* k, u16* v) {
  const int z = blockIdx.z;
  const u16* A = z == 0 ? xq : (z == 1 ? xk : xv);
  const u16* W = z == 0 ? wq : (z == 1 ? wk : wv);
  const float* bb = z == 0 ? bq : (z == 1 ? bk : bv);
  u16* o = z == 0 ? q : (z == 1 ? k : v);
  const float sc = z == 0 ? 0.125f : 1.0f;
  gemm_core<1>(A, W, bb, o, sc);
}

__global__ __launch_bounds__(256) void gemm_o(const u16* ctx, const u16* wo,
                                              const float* ob, float* out) {
  gemm_core<0>(ctx, wo, ob, out, 1.0f);
}

// ---- V transpose: (bh,S,HD) -> (bh,HD,S), bf16 -----------------------------
__global__ __launch_bounds__(256) void transpose_v(const u16* __restrict__ v,
                                                   u16* __restrict__ vt) {
  __shared__ u16 T[64][72];
  const int tid = threadIdx.x;
  const int bh = blockIdx.y, s0 = blockIdx.x * 64;
#pragma unroll
  for (int i = 0; i < 2; ++i) {
    const int L = i * 256 + tid, key = L >> 3, dc = L & 7;
    const uint4 val = *(const uint4*)&v[((size_t)bh * 2048 + s0 + key) * 64 + dc * 8];
    *(uint4*)&T[key][dc * 8] = val;
  }
  __syncthreads();
#pragma unroll
  for (int i = 0; i < 2; ++i) {
    const int L = i * 256 + tid, d = L >> 3, kc = L & 7;
    u16 tmp[8];
#pragma unroll
    for (int j = 0; j < 8; ++j) tmp[j] = T[kc * 8 + j][d];
    *(uint4*)&vt[((size_t)bh * 64 + d) * 2048 + s0 + kc * 8] = *(const uint4*)tmp;
  }
}

// ---- flash attention: 64 q-rows/block (16/wave), 64-key tiles --------------
// Round-2 structure + T4 counted-vmcnt barrier: the end-of-tile barrier waits
// ONLY on the 4 staging gld_lds (vmcnt(8)); the 8 bias/mask prefetch loads
// stay in flight across the barrier (compiler waits at their use next tile).
// Issue order staging->bias is pinned by sched_barrier(0) so the oldest-4
// VMEM ops at the wait are exactly the staging loads.
__global__ __launch_bounds__(256) void attn(const u16* __restrict__ Qb,
    const u16* __restrict__ Kb, const u16* __restrict__ VT,
    const float* __restrict__ bias, const int* __restrict__ kpm,
    u16* __restrict__ ctx) {
  __shared__ __align__(16) u16 Ks[2][4096];  // [c0..7][key0..63]*8
  __shared__ __align__(16) u16 Vs[2][4096];  // [kc0..7][d0..63]*8
  __shared__ __align__(16) u16 Ps[4096];     // [kc0..7][q0..63]*8 (wave-private rows)
  const int tid = threadIdx.x;
  const int w = tid >> 6, lane = tid & 63, ln = lane & 15, quad = lane >> 4;
  const int q0 = blockIdx.x * 64;
  const int hb = blockIdx.y, h = hb >> 1, b = hb & 1, bh = b * 16 + h;
  const int wr = w * 16;            // wave's 16 q-rows within tile

  short8 qf[2];                      // B-frag: col = q = wr+ln, c = ks*32+quad*8
#pragma unroll
  for (int ks = 0; ks < 2; ++ks)
    qf[ks] = *(const short8*)&Qb[((size_t)bh * 2048 + q0 + wr + ln) * 64 +
                                 ks * 32 + quad * 8];
  float mi = -3.0e38f, li = 0.f;     // per-lane: q = q0+wr+ln
  fx4 O[4] = {};                     // O[nt][r]: q = quad*4+r, d = nt*16+ln

  const int L0 = w * 64 + lane, L1 = L0 + 256;
  const u16* sk0 = Kb + ((size_t)bh * 2048 + (L0 & 63)) * 64 + (L0 >> 6) * 8;
  const u16* sk1 = Kb + ((size_t)bh * 2048 + (L1 & 63)) * 64 + (L1 >> 6) * 8;
  const u16* sv0 = VT + ((size_t)bh * 64 + (L0 & 63)) * 2048 + (L0 >> 6) * 8;
  const u16* sv1 = VT + ((size_t)bh * 64 + (L1 & 63)) * 2048 + (L1 >> 6) * 8;
  const int d0 = (w * 64) * 8, d1 = (256 + w * 64) * 8;

  // per-lane bias base: row q = q0+wr+ln, cols kt + nt*16 + quad*4 (+0..3)
  const float* bp = bias + (size_t)h * Ss * Ss + (size_t)(q0 + wr + ln) * Ss + quad * 4;
  const int* mp = kpm + b * Ss + quad * 4;

  // prologue: stage K/V tile 0 into buffer 0; bias+mask for tile 0 (full drain)
  gld_lds16(sk0, &Ks[0][d0]); gld_lds16(sk1, &Ks[0][d1]);
  gld_lds16(sv0, &Vs[0][d0]); gld_lds16(sv1, &Vs[0][d1]);
  fx4 bm[4];
#pragma unroll
  for (int nt = 0; nt < 4; ++nt) {
    const float4 bv = *(const float4*)(bp + nt * 16);
    const int4 mv = *(const int4*)(mp + nt * 16);
    bm[nt][0] = bv.x + (mv.x ? -1.0e30f : 0.0f);
    bm[nt][1] = bv.y + (mv.y ? -1.0e30f : 0.0f);
    bm[nt][2] = bv.z + (mv.z ? -1.0e30f : 0.0f);
    bm[nt][3] = bv.w + (mv.w ? -1.0e30f : 0.0f);
  }
  __syncthreads();

  for (int kt = 0; kt < Ss; kt += 64) {
    const int cur = (kt >> 6) & 1;
    // (1) staging for t+1 — MUST be the oldest outstanding VMEM at the wait
    if (kt + 64 < Ss) {
      const int nb = cur ^ 1;
      gld_lds16(sk0 + (size_t)(kt + 64) * 64, &Ks[nb][d0]);
      gld_lds16(sk1 + (size_t)(kt + 64) * 64, &Ks[nb][d1]);
      gld_lds16(sv0 + kt + 64, &Vs[nb][d0]);
      gld_lds16(sv1 + kt + 64, &Vs[nb][d1]);
    }
    __builtin_amdgcn_sched_barrier(0);  // pin: staging issued before bias
    // (2) bias/mask prefetch for t+1 (8 VMEM) — allowed to cross the barrier
    const int kn = (kt + 64 < Ss) ? kt + 64 : kt;
    fx4 bmn[4];
#pragma unroll
    for (int nt = 0; nt < 4; ++nt) {
      const float4 bv = *(const float4*)(bp + kn + nt * 16);
      const int4 mv = *(const int4*)(mp + kn + nt * 16);
      bmn[nt][0] = bv.x + (mv.x ? -1.0e30f : 0.0f);
      bmn[nt][1] = bv.y + (mv.y ? -1.0e30f : 0.0f);
      bmn[nt][2] = bv.z + (mv.z ? -1.0e30f : 0.0f);
      bmn[nt][3] = bv.w + (mv.w ? -1.0e30f : 0.0f);
    }

    // (3) S'[k][q] = K*Q: lane holds k = kt + nt*16 + quad*4 + r, q = q0+wr+ln
    fx4 S[4] = {};
#pragma unroll
    for (int ks = 0; ks < 2; ++ks)
#pragma unroll
      for (int nt = 0; nt < 4; ++nt) {
        const short8 kf = *(const short8*)&Ks[cur][((ks * 4 + quad) * 64 + nt * 16 + ln) * 8];
        S[nt] = MFMA16(kf, qf[ks], S[nt]);
      }

    // lane-local softmax over the lane's 16 scores
    float pmax = -3.0e38f;
#pragma unroll
    for (int nt = 0; nt < 4; ++nt)
#pragma unroll
      for (int r = 0; r < 4; ++r) {
        S[nt][r] += bm[nt][r];
        pmax = fmaxf(pmax, S[nt][r]);
      }
    pmax = fmaxf(pmax, __shfl_xor(pmax, 16));
    pmax = fmaxf(pmax, __shfl_xor(pmax, 32));

    // defer-max: only rescale when the running max grew by > 8
    if (!__all(pmax <= mi + 8.0f)) {
      const float mn = fmaxf(mi, pmax);
      const float a = __expf(mi - mn);
#pragma unroll
      for (int r = 0; r < 4; ++r) {
        const float ar = __shfl(a, quad * 4 + r);
#pragma unroll
        for (int nt = 0; nt < 4; ++nt) O[nt][r] *= ar;
      }
      li *= a;
      mi = mn;
    }

    float rs = 0.f;
#pragma unroll
    for (int nt = 0; nt < 4; ++nt)
#pragma unroll
      for (int r = 0; r < 4; ++r) {
        S[nt][r] = __expf(S[nt][r] - mi);
        rs += S[nt][r];
      }
    rs += __shfl_xor(rs, 16);
    rs += __shfl_xor(rs, 32);
    li += rs;

    // pack P -> bf16 and write lane's 4 runs of 4 consecutive k's (b64 each)
#pragma unroll
    for (int nt = 0; nt < 4; ++nt) {
      unsigned int u0, u1;
      asm("v_cvt_pk_bf16_f32 %0, %1, %2" : "=v"(u0) : "v"(S[nt][0]), "v"(S[nt][1]));
      asm("v_cvt_pk_bf16_f32 %0, %1, %2" : "=v"(u1) : "v"(S[nt][2]), "v"(S[nt][3]));
      const int kcb = nt * 2 + (quad >> 1);          // k>>3
      uint2 pk; pk.x = u0; pk.y = u1;
      *(uint2*)&Ps[(kcb * 64 + wr + ln) * 8 + (quad & 1) * 4] = pk;
    }

#pragma unroll
    for (int ks = 0; ks < 2; ++ks) {
      const short8 pf = *(const short8*)&Ps[((ks * 4 + quad) * 64 + wr + ln) * 8];
#pragma unroll
      for (int nt = 0; nt < 4; ++nt) {
        const short8 vf = *(const short8*)&Vs[cur][((ks * 4 + quad) * 64 + nt * 16 + ln) * 8];
        O[nt] = MFMA16(pf, vf, O[nt]);
      }
    }

#pragma unroll
    for (int nt = 0; nt < 4; ++nt) bm[nt] = bmn[nt];

    // (4) T4 counted-vmcnt barrier: wait ONLY for the 4 staging gld_lds
    // (8 bias/mask loads stay outstanding across the barrier).
    __builtin_amdgcn_sched_barrier(0);
    asm volatile("s_waitcnt vmcnt(8)" ::: "memory");
    __builtin_amdgcn_s_barrier();
    __builtin_amdgcn_sched_barrier(0);
  }

#pragma unroll
  for (int r = 0; r < 4; ++r) {
    const float lr = __shfl(li, quad * 4 + r);
    const float inv = 1.0f / fmaxf(lr, 1e-6f);
    const int qg = q0 + wr + quad * 4 + r;
#pragma unroll
    for (int nt = 0; nt < 4; ++nt)
      ctx[((size_t)(b * Ss + qg)) * 1024 + h * 64 + nt * 16 + ln] =
          f2bf(O[nt][r] * inv);
  }
}

// ---- launch ----------------------------------------------------------------
extern "C" void kernel_launch(void* const* d_in, const int* in_sizes, int n_in,
                              void* d_out, int out_size, void* d_ws, size_t ws_size,
                              hipStream_t stream) {
  const float* query = (const float*)d_in[0];
  const float* key   = (const float*)d_in[1];
  const float* value = (const float*)d_in[2];
  const int*   kpm   = (const int*)d_in[3];
  const float* bias  = (const float*)d_in[4];
  const float* q_w   = (const float*)d_in[5];
  const float* q_b   = (const float*)d_in[6];
  const float* k_w   = (const float*)d_in[7];
  const float* k_b   = (const float*)d_in[8];
  const float* v_w   = (const float*)d_in[9];
  const float* v_b   = (const float*)d_in[10];
  const float* o_w   = (const float*)d_in[11];
  const float* o_b   = (const float*)d_in[12];
  float* out = (float*)d_out;

  char* ws = (char*)d_ws;
  const size_t MB = 1024 * 1024;
  u16* xq = (u16*)(ws + 0 * MB);
  u16* xk = (u16*)(ws + 8 * MB);
  u16* xv = (u16*)(ws + 16 * MB);
  u16* wq = (u16*)(ws + 24 * MB);
  u16* wk = (u16*)(ws + 26 * MB);
  u16* wv = (u16*)(ws + 28 * MB);
  u16* wo = (u16*)(ws + 30 * MB);
  u16* qb = (u16*)(ws + 32 * MB);
  u16* kb = (u16*)(ws + 40 * MB);
  u16* vb = (u16*)(ws + 48 * MB);
  u16* cx = (u16*)(ws + 56 * MB);
  u16* vt = (u16*)(ws + 0 * MB);     // alias xq (dead after gemm_qkv)

  prep<<<dim3(16384), 256, 0, stream>>>(query, key, value, q_w, k_w, v_w, o_w,
                                        xq, xk, xv, wq, wk, wv, wo);
  gemm_qkv<<<dim3(8, 32, 3), 256, 0, stream>>>(xq, xk, xv, wq, wk, wv,
                                               q_b, k_b, v_b, qb, kb, vb);
  transpose_v<<<dim3(32, 32), 256, 0, stream>>>(vb, vt);
  attn<<<dim3(32, 32), 256, 0, stream>>>(qb, kb, vt, bias, kpm, cx);
  gemm_o<<<dim3(8, 32), 256, 0, stream>>>(cx, wo, o_b, out);
}